// Round 20
// baseline (2169.473 us; speedup 1.0000x reference)
//
#include <hip/hip_runtime.h>

#define NN 100000
#define NE 1600000
#define FEAT 128
#define NGRAPH 128
#define BSHIFT 9
#define NB 196          // ceil(NN / 512)
#define NCHUNK 400
#define CHUNK 4000      // NE / NCHUNK exactly

typedef __attribute__((ext_vector_type(8))) short bf16x8;
typedef __attribute__((ext_vector_type(4))) float f32x4;
typedef __attribute__((ext_vector_type(4))) unsigned u32x4;

union U4 { u32x4 u; bf16x8 v; };

__device__ __forceinline__ unsigned short f2bf(float f) {
    unsigned u = __float_as_uint(f);
    return (unsigned short)((u + 0x7fffu + ((u >> 16) & 1u)) >> 16);  // RNE
}
__device__ __forceinline__ float bf2f(unsigned short h) {
    return __uint_as_float(((unsigned)h) << 16);
}
__device__ __forceinline__ unsigned packbf(float f) {
    unsigned short h = f2bf(f);
    return (unsigned)h | ((unsigned)f2bf(f - bf2f(h)) << 16);
}
__device__ __forceinline__ uint2 unpack2(unsigned p0, unsigned p1) {
    return make_uint2((p0 & 0xffffu) | (p1 << 16), (p0 >> 16) | (p1 & 0xffff0000u));
}
__device__ __forceinline__ void unpack8(u32x4 a, u32x4 b, bf16x8& hv, bf16x8& lv) {
    uint2 r0 = unpack2(a.x, a.y), r1 = unpack2(a.z, a.w);
    uint2 r2 = unpack2(b.x, b.y), r3 = unpack2(b.z, b.w);
    U4 h, l;
    h.u = (u32x4){r0.x, r1.x, r2.x, r3.x};
    l.u = (u32x4){r0.y, r1.y, r2.y, r3.y};
    hv = h.v; lv = l.v;
}

// ==================== W hi/lo split -> fragment-major layout (all 6 weights, 1 launch) ====================
__global__ __launch_bounds__(256)
void wsplit6_kernel(const float* __restrict__ W0, const float* __restrict__ W1,
                    const float* __restrict__ W2, const float* __restrict__ W3,
                    const float* __restrict__ W4, const float* __restrict__ W5,
                    short* __restrict__ wbase)
{
    const int widx = blockIdx.x >> 6;            // 64 blocks per weight (16384/256)
    const int i = (blockIdx.x & 63) * 256 + threadIdx.x;
    const float* W = widx == 0 ? W0 : widx == 1 ? W1 : widx == 2 ? W2
                   : widx == 3 ? W3 : widx == 4 ? W4 : W5;
    short* Wf = wbase + (size_t)widx * 2 * 16384;
    int o = i >> 7, k = i & 127;
    float f = W[i];
    unsigned short h = f2bf(f);
    short lo = (short)f2bf(f - bf2f(h));
    int ct = o >> 4, lr = o & 15, kc = k >> 5, q = (k >> 3) & 3, j = k & 7;
    int idx = (kc * 8 + ct) * 512 + ((q << 4) | lr) * 8 + j;
    Wf[idx] = (short)h;
    Wf[16384 + idx] = lo;
}

// ==================== radix-partition CSR build ====================
__global__ __launch_bounds__(256)
void p1a_count(const int* __restrict__ ei, int* __restrict__ cnt_T)
{
    __shared__ int hist[NB];
    const int b = blockIdx.x, tid = threadIdx.x;
    for (int i = tid; i < NB; i += 256) hist[i] = 0;
    __syncthreads();
    const int e0 = b * CHUNK;
    for (int e = e0 + tid; e < e0 + CHUNK; e += 256)
        atomicAdd(&hist[ei[NE + e] >> BSHIFT], 1);
    __syncthreads();
    for (int k = tid; k < NB; k += 256) cnt_T[k * NCHUNK + b] = hist[k];
}

__global__ __launch_bounds__(1024)
void scan1_kernel(const int* __restrict__ in, int* __restrict__ out,
                  int* __restrict__ bsum, int n)
{
    __shared__ int sh[1024];
    const int tid = threadIdx.x;
    const int gid = blockIdx.x * 1024 + tid;
    int v = (gid < n) ? in[gid] : 0;
    sh[tid] = v;
    __syncthreads();
    #pragma unroll
    for (int d = 1; d < 1024; d <<= 1) {
        int t = (tid >= d) ? sh[tid - d] : 0;
        __syncthreads();
        sh[tid] += t;
        __syncthreads();
    }
    if (gid < n) out[gid] = sh[tid] - v;
    if (tid == 1023) bsum[blockIdx.x] = sh[1023];
}

__global__ __launch_bounds__(128)
void scan2_kernel(int* __restrict__ bsum, int nb)
{
    __shared__ int sh[128];
    const int tid = threadIdx.x;
    int v = (tid < nb) ? bsum[tid] : 0;
    sh[tid] = v;
    __syncthreads();
    #pragma unroll
    for (int d = 1; d < 128; d <<= 1) {
        int t = (tid >= d) ? sh[tid - d] : 0;
        __syncthreads();
        sh[tid] += t;
        __syncthreads();
    }
    if (tid < nb) bsum[tid] = sh[tid] - v;
}

__global__ __launch_bounds__(1024)
void scan3g_kernel(int* __restrict__ arr, const int* __restrict__ bsum, int n)
{
    const int gid = blockIdx.x * 1024 + threadIdx.x;
    if (gid < n) arr[gid] += bsum[blockIdx.x];
}

__global__ __launch_bounds__(256)
void p1b_scatter(const int* __restrict__ ei, const int* __restrict__ offs_T,
                 int2* __restrict__ ebuf)
{
    __shared__ int cur[NB];
    const int b = blockIdx.x, tid = threadIdx.x;
    for (int i = tid; i < NB; i += 256) cur[i] = offs_T[i * NCHUNK + b];
    __syncthreads();
    const int e0 = b * CHUNK;
    for (int e = e0 + tid; e < e0 + CHUNK; e += 256) {
        int s = ei[e], d = ei[NE + e];
        int pos = atomicAdd(&cur[d >> BSHIFT], 1);
        ebuf[pos] = make_int2(s, d);
    }
}

__global__ __launch_bounds__(512)
void p2_csr(const int2* __restrict__ ebuf, const int* __restrict__ offs_T,
            int* __restrict__ off, int* __restrict__ csr)
{
    __shared__ int degc[512];
    __shared__ int sh[512];
    const int k = blockIdx.x, tid = threadIdx.x;
    const int base = k << BSHIFT;
    const int bs = offs_T[k * NCHUNK];
    const int be = (k == NB - 1) ? NE : offs_T[(k + 1) * NCHUNK];
    degc[tid] = 0;
    __syncthreads();
    for (int e = bs + tid; e < be; e += 512)
        atomicAdd(&degc[ebuf[e].y - base], 1);
    __syncthreads();
    int v = degc[tid];
    sh[tid] = v;
    __syncthreads();
    #pragma unroll
    for (int d = 1; d < 512; d <<= 1) {
        int t = (tid >= d) ? sh[tid - d] : 0;
        __syncthreads();
        sh[tid] += t;
        __syncthreads();
    }
    const int excl = bs + sh[tid] - v;
    const int n = base + tid;
    if (n <= NN) off[n] = excl;
    degc[tid] = excl;
    __syncthreads();
    for (int e = bs + tid; e < be; e += 512) {
        int2 p = ebuf[e];
        int slot = atomicAdd(&degc[p.y - base], 1);
        csr[slot] = p.x;
    }
}

// ==================== megakernel: gather + GIN update + 2 GEMMs, one layer ====================
// 512 thr = 8 waves x 16 rows = 128 rows/block. 64 KB LDS (W only).
// __launch_bounds__(512, 2): 2nd arg = min BLOCKS/CU (hipcc CUDA semantics, measured R14:
// arg 4 -> 64-VGPR cap -> 650 MB spill). 2 blocks/CU -> 128-VGPR cap, fits ~100 live regs.
__global__ __launch_bounds__(512, 2)
void layer_mega_kernel(const float* __restrict__ h, const int* __restrict__ off,
                       const int* __restrict__ csr,
                       const short* __restrict__ Wf1, const short* __restrict__ Wf2,
                       const float* __restrict__ b1, const float* __restrict__ b2,
                       float* __restrict__ outC, int n_nodes)
{
    __shared__ short wlds[32768];   // 64 KB frag-major [hi|lo]
    const int tid = threadIdx.x;
    const int lane = tid & 63;
    const int w = tid >> 6;
    const int lr = lane & 15;
    const int lq = lane >> 4;
    const int rowbase = blockIdx.x * 128 + w * 16;

    // stage W1 (drains under the gather phase; barrier after phase A)
    {
        const bf16x8* src = reinterpret_cast<const bf16x8*>(Wf1);
        bf16x8* dst = reinterpret_cast<bf16x8*>(wlds);
        #pragma unroll
        for (int it = 0; it < 8; ++it)
            dst[it * 512 + tid] = src[it * 512 + tid];
    }

    // ---- phase A: gather + GIN update, one (wave-uniform) row at a time ----
    unsigned areg[32] = {};
    #pragma unroll
    for (int r = 0; r < 16; ++r) {
        const int row = rowbase + r;
        float2 acc = make_float2(0.f, 0.f);
        if (row < n_nodes) {
            const int s = off[row], e = off[row + 1];
            for (int base = s; base < e; base += 64) {
                const int cnt = min(64, e - base);
                int src_l = (base + lane < e) ? csr[base + lane] : 0;
                for (int jb = 0; jb < cnt; jb += 16) {
                    float2 v[16];
                    #pragma unroll
                    for (int q = 0; q < 16; ++q) {
                        int sq = __shfl(src_l, (jb + q) & 63);
                        v[q] = reinterpret_cast<const float2*>(h + (size_t)sq * FEAT)[lane];
                    }
                    #pragma unroll
                    for (int q = 0; q < 16; ++q)
                        if (jb + q < cnt) { acc.x += v[q].x; acc.y += v[q].y; }
                }
            }
            float2 hv = reinterpret_cast<const float2*>(h + (size_t)row * FEAT)[lane];
            acc.x = (hv.x + acc.x) * 0.5f + hv.x;
            acc.y = (hv.y + acc.y) * 0.5f + hv.y;
        }
        unsigned px = packbf(acc.x), py = packbf(acc.y);
        // owner lanes (lr == r): feature kc*32+lq*8+2t+c from lane kc*16+lq*4+t
        #pragma unroll
        for (int kc = 0; kc < 4; ++kc) {
            #pragma unroll
            for (int t = 0; t < 4; ++t) {
                const int srcl = kc * 16 + lq * 4 + t;
                unsigned sx = __shfl(px, srcl);
                unsigned sy = __shfl(py, srcl);
                if (lr == r) {
                    areg[kc * 8 + 2 * t]     = sx;
                    areg[kc * 8 + 2 * t + 1] = sy;
                }
            }
        }
    }
    __syncthreads();   // W1 staged, all waves ready

    // ---- GEMM1 (swapped operands: D = W1 · xeff^T) ----
    f32x4 acc1[8] = {};
    #pragma unroll
    for (int kc = 0; kc < 4; ++kc) {
        u32x4 qa = {areg[kc * 8 + 0], areg[kc * 8 + 1], areg[kc * 8 + 2], areg[kc * 8 + 3]};
        u32x4 qb = {areg[kc * 8 + 4], areg[kc * 8 + 5], areg[kc * 8 + 6], areg[kc * 8 + 7]};
        bf16x8 ah, al;
        unpack8(qa, qb, ah, al);
        #pragma unroll
        for (int ct = 0; ct < 8; ++ct) {
            const int ra = (kc * 8 + ct) * 512 + lane * 8;
            bf16x8 bh = *reinterpret_cast<const bf16x8*>(&wlds[ra]);
            bf16x8 bl = *reinterpret_cast<const bf16x8*>(&wlds[16384 + ra]);
            acc1[ct] = __builtin_amdgcn_mfma_f32_16x16x32_bf16(bh, ah, acc1[ct], 0, 0, 0);
            acc1[ct] = __builtin_amdgcn_mfma_f32_16x16x32_bf16(bh, al, acc1[ct], 0, 0, 0);
            acc1[ct] = __builtin_amdgcn_mfma_f32_16x16x32_bf16(bl, ah, acc1[ct], 0, 0, 0);
        }
    }

    // ---- h1 = relu(acc1 + b1), packed in regs ----
    unsigned h1p[32];
    #pragma unroll
    for (int ct = 0; ct < 8; ++ct) {
        const int c0 = ct * 16 + lq * 4;
        float4 bv = *reinterpret_cast<const float4*>(&b1[c0]);
        h1p[ct * 4 + 0] = packbf(fmaxf(acc1[ct][0] + bv.x, 0.f));
        h1p[ct * 4 + 1] = packbf(fmaxf(acc1[ct][1] + bv.y, 0.f));
        h1p[ct * 4 + 2] = packbf(fmaxf(acc1[ct][2] + bv.z, 0.f));
        h1p[ct * 4 + 3] = packbf(fmaxf(acc1[ct][3] + bv.w, 0.f));
    }

    // ---- stage W2 over W1 ----
    __syncthreads();   // all W1 LDS reads complete
    {
        const bf16x8* src = reinterpret_cast<const bf16x8*>(Wf2);
        bf16x8* dst = reinterpret_cast<bf16x8*>(wlds);
        #pragma unroll
        for (int it = 0; it < 8; ++it)
            dst[it * 512 + tid] = src[it * 512 + tid];
    }
    __syncthreads();

    // ---- GEMM2: B-frag from h1p via 4-lane shfl ----
    f32x4 acc2[8] = {};
    const int aown = (lq & 1) * 2;
    const bool hi_t = (lq & 2) != 0;
    #pragma unroll
    for (int kc = 0; kc < 4; ++kc) {
        unsigned pd[8];
        #pragma unroll
        for (int m = 0; m < 4; ++m) {
            unsigned vA = h1p[(2 * kc) * 4 + m];
            unsigned vB = h1p[(2 * kc + 1) * 4 + m];
            unsigned sA0 = __shfl(vA, lr + 16 * aown);
            unsigned sB0 = __shfl(vB, lr + 16 * aown);
            unsigned sA1 = __shfl(vA, lr + 16 * (aown + 1));
            unsigned sB1 = __shfl(vB, lr + 16 * (aown + 1));
            pd[m]     = hi_t ? sB0 : sA0;
            pd[4 + m] = hi_t ? sB1 : sA1;
        }
        u32x4 qa = {pd[0], pd[1], pd[2], pd[3]};
        u32x4 qb = {pd[4], pd[5], pd[6], pd[7]};
        bf16x8 hh, hl;
        unpack8(qa, qb, hh, hl);
        #pragma unroll
        for (int ct = 0; ct < 8; ++ct) {
            const int ra = (kc * 8 + ct) * 512 + lane * 8;
            bf16x8 bh = *reinterpret_cast<const bf16x8*>(&wlds[ra]);
            bf16x8 bl = *reinterpret_cast<const bf16x8*>(&wlds[16384 + ra]);
            acc2[ct] = __builtin_amdgcn_mfma_f32_16x16x32_bf16(bh, hh, acc2[ct], 0, 0, 0);
            acc2[ct] = __builtin_amdgcn_mfma_f32_16x16x32_bf16(bh, hl, acc2[ct], 0, 0, 0);
            acc2[ct] = __builtin_amdgcn_mfma_f32_16x16x32_bf16(bl, hh, acc2[ct], 0, 0, 0);
        }
    }

    // ---- epilogue: fp32 out ----
    const int n0 = rowbase + lr;
    if (n0 < n_nodes) {
        #pragma unroll
        for (int ct = 0; ct < 8; ++ct) {
            const int c0 = ct * 16 + lq * 4;
            float4 bv = *reinterpret_cast<const float4*>(&b2[c0]);
            float4 o;
            o.x = fmaxf(acc2[ct][0] + bv.x, 0.f);
            o.y = fmaxf(acc2[ct][1] + bv.y, 0.f);
            o.z = fmaxf(acc2[ct][2] + bv.z, 0.f);
            o.w = fmaxf(acc2[ct][3] + bv.w, 0.f);
            *reinterpret_cast<float4*>(&outC[(size_t)n0 * FEAT + c0]) = o;
        }
    }
}

// ==================== pooling ====================
__global__ __launch_bounds__(512)
void pool_kernel(const float* __restrict__ y, const int* __restrict__ batch,
                 float* __restrict__ out, int n_nodes, int layer)
{
    const int g = blockIdx.x;
    int lo = 0, hi = n_nodes;
    while (lo < hi) { int mid = (lo + hi) >> 1; if (batch[mid] < g) lo = mid + 1; else hi = mid; }
    const int start = lo;
    hi = n_nodes;
    while (lo < hi) { int mid = (lo + hi) >> 1; if (batch[mid] < g + 1) lo = mid + 1; else hi = mid; }
    const int end = lo;

    const int tid = threadIdx.x;
    const int f = tid & 127;
    const int q = tid >> 7;
    float sum = 0.f;
    for (int n = start + q; n < end; n += 4)
        sum += y[(size_t)n * FEAT + f];

    __shared__ float red[512];
    red[tid] = sum;
    __syncthreads();
    if (tid < 128)
        out[g * (3 * FEAT) + layer * FEAT + tid]
            = red[tid] + red[tid + 128] + red[tid + 256] + red[tid + 384];
}

// ==================== fallback path kernels (ws too small) ====================
__global__ __launch_bounds__(256)
void scatter_kernel(const float* __restrict__ h, const int* __restrict__ ei,
                    float* __restrict__ agg, int n_edges)
{
    int e = blockIdx.x * 4 + (threadIdx.x >> 6);
    if (e >= n_edges) return;
    int lane = threadIdx.x & 63;
    int s = ei[e];
    int d = ei[n_edges + e];
    float2 v = reinterpret_cast<const float2*>(h + (size_t)s * FEAT)[lane];
    float* ap = agg + (size_t)d * FEAT + lane * 2;
    atomicAdd(ap, v.x);
    atomicAdd(ap + 1, v.y);
}

__global__ __launch_bounds__(256)
void combine_kernel(const float* __restrict__ h, float* __restrict__ agg_xeff, size_t n4)
{
    size_t i = (size_t)blockIdx.x * 256 + threadIdx.x;
    if (i >= n4) return;
    float4 a = reinterpret_cast<const float4*>(h)[i];
    float4 g = reinterpret_cast<float4*>(agg_xeff)[i];
    float4 o;
    o.x = (a.x + g.x) * 0.5f + a.x;
    o.y = (a.y + g.y) * 0.5f + a.y;
    o.z = (a.z + g.z) * 0.5f + a.z;
    o.w = (a.w + g.w) * 0.5f + a.w;
    reinterpret_cast<float4*>(agg_xeff)[i] = o;
}

__global__ __launch_bounds__(256, 2)
void gemm_relu_kernel(const float* __restrict__ A, const float* __restrict__ W,
                      const float* __restrict__ bias, float* __restrict__ out, int n_nodes)
{
    __shared__ float xt[64][128];
    __shared__ float wt[64][128];
    const int tid = threadIdx.x;
    const int row0 = blockIdx.x * 128;
    const int r  = tid >> 1;
    const int ks = (tid & 1) << 5;
    const int tn = (tid >> 4) << 3;
    const int to = (tid & 15) << 3;
    float acc[8][8] = {};

    for (int c = 0; c < 2; ++c) {
        const int k0 = c * 64;
        {
            const float4* wrow = reinterpret_cast<const float4*>(W + r * FEAT + k0 + ks);
            #pragma unroll
            for (int i = 0; i < 8; ++i) {
                float4 w4 = wrow[i];
                int kk = ks + i * 4;
                wt[kk + 0][r] = w4.x; wt[kk + 1][r] = w4.y;
                wt[kk + 2][r] = w4.z; wt[kk + 3][r] = w4.w;
            }
        }
        {
            const int n = row0 + r;
            if (n < n_nodes) {
                const float4* ar = reinterpret_cast<const float4*>(A + (size_t)n * FEAT + k0 + ks);
                #pragma unroll
                for (int i = 0; i < 8; ++i) {
                    float4 a4 = ar[i];
                    int kk = ks + i * 4;
                    xt[kk + 0][r] = a4.x; xt[kk + 1][r] = a4.y;
                    xt[kk + 2][r] = a4.z; xt[kk + 3][r] = a4.w;
                }
            } else {
                #pragma unroll
                for (int i = 0; i < 8; ++i) {
                    int kk = ks + i * 4;
                    xt[kk + 0][r] = 0.f; xt[kk + 1][r] = 0.f;
                    xt[kk + 2][r] = 0.f; xt[kk + 3][r] = 0.f;
                }
            }
        }
        __syncthreads();
        #pragma unroll 4
        for (int k = 0; k < 64; ++k) {
            float4 x0 = *reinterpret_cast<const float4*>(&xt[k][tn]);
            float4 x1 = *reinterpret_cast<const float4*>(&xt[k][tn + 4]);
            float4 w0 = *reinterpret_cast<const float4*>(&wt[k][to]);
            float4 w1 = *reinterpret_cast<const float4*>(&wt[k][to + 4]);
            float xv[8] = {x0.x, x0.y, x0.z, x0.w, x1.x, x1.y, x1.z, x1.w};
            float wv[8] = {w0.x, w0.y, w0.z, w0.w, w1.x, w1.y, w1.z, w1.w};
            #pragma unroll
            for (int i = 0; i < 8; ++i)
                #pragma unroll
                for (int j = 0; j < 8; ++j)
                    acc[i][j] = fmaf(xv[i], wv[j], acc[i][j]);
        }
        __syncthreads();
    }

    float bv[8];
    #pragma unroll
    for (int j = 0; j < 8; ++j) bv[j] = bias[to + j];
    #pragma unroll
    for (int i = 0; i < 8; ++i) {
        int n = row0 + tn + i;
        if (n >= n_nodes) break;
        float4 o0, o1;
        o0.x = fmaxf(acc[i][0] + bv[0], 0.f);
        o0.y = fmaxf(acc[i][1] + bv[1], 0.f);
        o0.z = fmaxf(acc[i][2] + bv[2], 0.f);
        o0.w = fmaxf(acc[i][3] + bv[3], 0.f);
        o1.x = fmaxf(acc[i][4] + bv[4], 0.f);
        o1.y = fmaxf(acc[i][5] + bv[5], 0.f);
        o1.z = fmaxf(acc[i][6] + bv[6], 0.f);
        o1.w = fmaxf(acc[i][7] + bv[7], 0.f);
        float* op = out + (size_t)n * FEAT + to;
        *reinterpret_cast<float4*>(op) = o0;
        *reinterpret_cast<float4*>(op + 4) = o1;
    }
}

extern "C" void kernel_launch(void* const* d_in, const int* in_sizes, int n_in,
                              void* d_out, int out_size, void* d_ws, size_t ws_size,
                              hipStream_t stream)
{
    const float* x     = (const float*)d_in[0];
    const int*   ei    = (const int*)d_in[1];
    const int*   batch = (const int*)d_in[2];
    const float* W1[3] = {(const float*)d_in[4], (const float*)d_in[8],  (const float*)d_in[12]};
    const float* b1[3] = {(const float*)d_in[5], (const float*)d_in[9],  (const float*)d_in[13]};
    const float* W2[3] = {(const float*)d_in[6], (const float*)d_in[10], (const float*)d_in[14]};
    const float* b2[3] = {(const float*)d_in[7], (const float*)d_in[11], (const float*)d_in[15]};

    const size_t nf = (size_t)NN * FEAT;
    float* outp = (float*)d_out;
    const int mega_grid = (NN + 127) / 128;          // 782
    const int M = NB * NCHUNK;                       // 78400
    const int scanM_blocks = (M + 1023) / 1024;      // 77
    const int WN = FEAT * FEAT;                      // 16384

    // need: 2 ping-pong fp32 buffers + off + csr + split weights
    const size_t need_full = 2 * nf * 4 + (size_t)(NN + 1 + NE) * 4 + (size_t)12 * WN * 2;

    if (ws_size >= need_full) {
        float* bufC  = (float*)d_ws;             // nf floats
        float* bufD  = bufC + nf;                // nf floats
        int* off     = (int*)(bufD + nf);        // NN+1
        int* csr     = off + (NN + 1);           // NE
        short* wbase = (short*)(csr + NE);       // 12 * WN shorts
        short* wf[6];
        for (int i = 0; i < 6; ++i) wf[i] = wbase + (size_t)i * 2 * WN;
        // build transients aliased into bufD (overwritten only at layer-1 output)
        int2* ebuf  = (int2*)bufD;               // NE pairs (12.8 MB)
        int* cnt_T  = (int*)(ebuf + NE);         // M
        int* offs_T = cnt_T + M;                 // M
        int* bsum   = offs_T + M;                // 77

        wsplit6_kernel<<<6 * (WN / 256), 256, 0, stream>>>(W1[0], W2[0], W1[1], W2[1],
                                                           W1[2], W2[2], wbase);

        p1a_count<<<NCHUNK, 256, 0, stream>>>(ei, cnt_T);
        scan1_kernel<<<scanM_blocks, 1024, 0, stream>>>(cnt_T, offs_T, bsum, M);
        scan2_kernel<<<1, 128, 0, stream>>>(bsum, scanM_blocks);
        scan3g_kernel<<<scanM_blocks, 1024, 0, stream>>>(offs_T, bsum, M);
        p1b_scatter<<<NCHUNK, 256, 0, stream>>>(ei, offs_T, ebuf);
        p2_csr<<<NB, 512, 0, stream>>>(ebuf, offs_T, off, csr);

        const float* h = x;
        float* bufs[2] = {bufC, bufD};
        for (int l = 0; l < 3; ++l) {
            float* out_l = bufs[l & 1];          // l=0: bufC (h=x), l=1: bufD, l=2: bufC
            layer_mega_kernel<<<mega_grid, 512, 0, stream>>>(h, off, csr, wf[2 * l], wf[2 * l + 1],
                                                             b1[l], b2[l], out_l, NN);
            pool_kernel<<<NGRAPH, 512, 0, stream>>>(out_l, batch, outp, NN, l);
            h = out_l;
        }
    } else if (ws_size >= 3 * nf * 4) {
        float* bufA = (float*)d_ws;
        float* bufB = bufA + nf;
        float* bufC = bufB + nf;
        const int gg = (NN + 127) / 128;
        const float* h = x;
        for (int l = 0; l < 3; ++l) {
            hipMemsetAsync(bufA, 0, nf * 4, stream);
            scatter_kernel<<<(NE + 3) / 4, 256, 0, stream>>>(h, ei, bufA, NE);
            combine_kernel<<<(int)((nf / 4 + 255) / 256), 256, 0, stream>>>(h, bufA, nf / 4);
            gemm_relu_kernel<<<gg, 256, 0, stream>>>(bufA, W1[l], b1[l], bufB, NN);
            gemm_relu_kernel<<<gg, 256, 0, stream>>>(bufB, W2[l], b2[l], bufC, NN);
            pool_kernel<<<NGRAPH, 512, 0, stream>>>(bufC, batch, outp, NN, l);
            h = bufC;
        }
    }
}

// Round 21
// 691.755 us; speedup vs baseline: 3.1362x; 3.1362x over previous
//
#include <hip/hip_runtime.h>

#define NN 100000
#define NE 1600000
#define FEAT 128
#define NGRAPH 128
#define BSHIFT 9
#define NB 196          // ceil(NN / 512)
#define NCHUNK 400
#define CHUNK 4000      // NE / NCHUNK exactly

typedef __attribute__((ext_vector_type(8))) short bf16x8;
typedef __attribute__((ext_vector_type(4))) float f32x4;
typedef __attribute__((ext_vector_type(4))) unsigned u32x4;

union U4 { u32x4 u; bf16x8 v; };

__device__ __forceinline__ unsigned short f2bf(float f) {
    unsigned u = __float_as_uint(f);
    return (unsigned short)((u + 0x7fffu + ((u >> 16) & 1u)) >> 16);  // RNE
}
__device__ __forceinline__ float bf2f(unsigned short h) {
    return __uint_as_float(((unsigned)h) << 16);
}
__device__ __forceinline__ unsigned packbf(float f) {
    unsigned short h = f2bf(f);
    return (unsigned)h | ((unsigned)f2bf(f - bf2f(h)) << 16);
}
__device__ __forceinline__ uint2 unpack2(unsigned p0, unsigned p1) {
    return make_uint2((p0 & 0xffffu) | (p1 << 16), (p0 >> 16) | (p1 & 0xffff0000u));
}
__device__ __forceinline__ void unpack8(u32x4 a, u32x4 b, bf16x8& hv, bf16x8& lv) {
    uint2 r0 = unpack2(a.x, a.y), r1 = unpack2(a.z, a.w);
    uint2 r2 = unpack2(b.x, b.y), r3 = unpack2(b.z, b.w);
    U4 h, l;
    h.u = (u32x4){r0.x, r1.x, r2.x, r3.x};
    l.u = (u32x4){r0.y, r1.y, r2.y, r3.y};
    hv = h.v; lv = l.v;
}

// ==================== W hi/lo split -> fragment-major layout ====================
__global__ __launch_bounds__(256)
void wsplit_frag_kernel(const float* __restrict__ W, short* __restrict__ Wf)
{
    int i = blockIdx.x * 256 + threadIdx.x;   // 16384 elements
    int o = i >> 7, k = i & 127;
    float f = W[i];
    unsigned short h = f2bf(f);
    short lo = (short)f2bf(f - bf2f(h));
    int ct = o >> 4, lr = o & 15, kc = k >> 5, q = (k >> 3) & 3, j = k & 7;
    int idx = (kc * 8 + ct) * 512 + ((q << 4) | lr) * 8 + j;
    Wf[idx] = (short)h;
    Wf[16384 + idx] = lo;
}

// ==================== radix-partition CSR build ====================
__global__ __launch_bounds__(256)
void p1a_count(const int* __restrict__ ei, int* __restrict__ cnt_T)
{
    __shared__ int hist[NB];
    const int b = blockIdx.x, tid = threadIdx.x;
    for (int i = tid; i < NB; i += 256) hist[i] = 0;
    __syncthreads();
    const int e0 = b * CHUNK;
    for (int e = e0 + tid; e < e0 + CHUNK; e += 256)
        atomicAdd(&hist[ei[NE + e] >> BSHIFT], 1);
    __syncthreads();
    for (int k = tid; k < NB; k += 256) cnt_T[k * NCHUNK + b] = hist[k];
}

__global__ __launch_bounds__(1024)
void scan1_kernel(const int* __restrict__ in, int* __restrict__ out,
                  int* __restrict__ bsum, int n)
{
    __shared__ int sh[1024];
    const int tid = threadIdx.x;
    const int gid = blockIdx.x * 1024 + tid;
    int v = (gid < n) ? in[gid] : 0;
    sh[tid] = v;
    __syncthreads();
    #pragma unroll
    for (int d = 1; d < 1024; d <<= 1) {
        int t = (tid >= d) ? sh[tid - d] : 0;
        __syncthreads();
        sh[tid] += t;
        __syncthreads();
    }
    if (gid < n) out[gid] = sh[tid] - v;
    if (tid == 1023) bsum[blockIdx.x] = sh[1023];
}

__global__ __launch_bounds__(128)
void scan2_kernel(int* __restrict__ bsum, int nb)
{
    __shared__ int sh[128];
    const int tid = threadIdx.x;
    int v = (tid < nb) ? bsum[tid] : 0;
    sh[tid] = v;
    __syncthreads();
    #pragma unroll
    for (int d = 1; d < 128; d <<= 1) {
        int t = (tid >= d) ? sh[tid - d] : 0;
        __syncthreads();
        sh[tid] += t;
        __syncthreads();
    }
    if (tid < nb) bsum[tid] = sh[tid] - v;
}

__global__ __launch_bounds__(1024)
void scan3g_kernel(int* __restrict__ arr, const int* __restrict__ bsum, int n)
{
    const int gid = blockIdx.x * 1024 + threadIdx.x;
    if (gid < n) arr[gid] += bsum[blockIdx.x];
}

__global__ __launch_bounds__(256)
void p1b_scatter(const int* __restrict__ ei, const int* __restrict__ offs_T,
                 int2* __restrict__ ebuf)
{
    __shared__ int cur[NB];
    const int b = blockIdx.x, tid = threadIdx.x;
    for (int i = tid; i < NB; i += 256) cur[i] = offs_T[i * NCHUNK + b];
    __syncthreads();
    const int e0 = b * CHUNK;
    for (int e = e0 + tid; e < e0 + CHUNK; e += 256) {
        int s = ei[e], d = ei[NE + e];
        int pos = atomicAdd(&cur[d >> BSHIFT], 1);
        ebuf[pos] = make_int2(s, d);
    }
}

__global__ __launch_bounds__(512)
void p2_csr(const int2* __restrict__ ebuf, const int* __restrict__ offs_T,
            int* __restrict__ off, int* __restrict__ csr)
{
    __shared__ int degc[512];
    __shared__ int sh[512];
    const int k = blockIdx.x, tid = threadIdx.x;
    const int base = k << BSHIFT;
    const int bs = offs_T[k * NCHUNK];
    const int be = (k == NB - 1) ? NE : offs_T[(k + 1) * NCHUNK];
    degc[tid] = 0;
    __syncthreads();
    for (int e = bs + tid; e < be; e += 512)
        atomicAdd(&degc[ebuf[e].y - base], 1);
    __syncthreads();
    int v = degc[tid];
    sh[tid] = v;
    __syncthreads();
    #pragma unroll
    for (int d = 1; d < 512; d <<= 1) {
        int t = (tid >= d) ? sh[tid - d] : 0;
        __syncthreads();
        sh[tid] += t;
        __syncthreads();
    }
    const int excl = bs + sh[tid] - v;
    const int n = base + tid;
    if (n <= NN) off[n] = excl;
    degc[tid] = excl;
    __syncthreads();
    for (int e = bs + tid; e < be; e += 512) {
        int2 p = ebuf[e];
        int slot = atomicAdd(&degc[p.y - base], 1);
        csr[slot] = p.x;
    }
}

// ==================== aggregation: xeff = (h + sum_in h[src]) * 0.5 + h, packed hi|lo ====================
__global__ __launch_bounds__(256)
void aggregate_pack_kernel(const float* __restrict__ h, const int* __restrict__ off,
                           const int* __restrict__ csr, unsigned* __restrict__ xP, int nn)
{
    const int node = blockIdx.x * 4 + (threadIdx.x >> 6);
    if (node >= nn) return;
    const int lane = threadIdx.x & 63;
    const int s = off[node], e = off[node + 1];
    float2 acc = make_float2(0.f, 0.f);
    for (int base = s; base < e; base += 64) {
        const int cnt = min(64, e - base);
        int src_l = (base + lane < e) ? csr[base + lane] : 0;
        for (int jb = 0; jb < cnt; jb += 16) {
            float2 v[16];
            #pragma unroll
            for (int q = 0; q < 16; ++q) {
                int sq = __shfl(src_l, (jb + q) & 63);
                v[q] = reinterpret_cast<const float2*>(h + (size_t)sq * FEAT)[lane];
            }
            #pragma unroll
            for (int q = 0; q < 16; ++q) {
                if (jb + q < cnt) { acc.x += v[q].x; acc.y += v[q].y; }
            }
        }
    }
    float2 hv = reinterpret_cast<const float2*>(h + (size_t)node * FEAT)[lane];
    float ox = (hv.x + acc.x) * 0.5f + hv.x;
    float oy = (hv.y + acc.y) * 0.5f + hv.y;
    uint2 pw = make_uint2(packbf(ox), packbf(oy));
    *reinterpret_cast<uint2*>(&xP[(size_t)node * FEAT + lane * 2]) = pw;
}

// ==================== fused layer: out = relu(relu(xeff@W1^T+b1)@W2^T+b2) ====================
// 512 threads = 8 waves x 16 rows = 128 rows/block. One row per lane.
// __launch_bounds__(512, 4): measured best (R13, 693 us) — the 64-VGPR cap's minor spill
// beats halved wave count (R15's (512,2) = 706 us).
__global__ __launch_bounds__(512, 4)
void layer_fused_kernel(const unsigned* __restrict__ aP, const short* __restrict__ Wf1,
                        const short* __restrict__ Wf2, const float* __restrict__ b1,
                        const float* __restrict__ b2, float* __restrict__ outC, int n_nodes)
{
    __shared__ short wlds[32768];   // 64 KB frag-major [hi|lo]
    const int tid = threadIdx.x;
    const int lane = tid & 63;
    const int w = tid >> 6;
    const int lr = lane & 15;
    const int lq = lane >> 4;
    const int n0 = blockIdx.x * 128 + w * 16 + lr;
    const bool v0 = (n0 < n_nodes);
    const size_t rb0 = (size_t)n0 * FEAT + lq * 8;
    u32x4 zz = {};

    // ---- stage W1 ----
    {
        const bf16x8* src = reinterpret_cast<const bf16x8*>(Wf1);
        bf16x8* dst = reinterpret_cast<bf16x8*>(wlds);
        #pragma unroll
        for (int it = 0; it < 8; ++it)
            dst[it * 512 + tid] = src[it * 512 + tid];
    }
    // prologue A load (kc=0) before barrier
    u32x4 paa = v0 ? *reinterpret_cast<const u32x4*>(&aP[rb0])     : zz;
    u32x4 pab = v0 ? *reinterpret_cast<const u32x4*>(&aP[rb0 + 4]) : zz;
    __syncthreads();

    // ---- GEMM1 (swapped operands: D = W1 · xeff^T) ----
    f32x4 acc[8] = {};
    bf16x8 ah, al;
    unpack8(paa, pab, ah, al);
    #pragma unroll
    for (int kc = 0; kc < 4; ++kc) {
        u32x4 na = zz, nb = zz;
        if (kc < 3) {
            const int ko = (kc + 1) * 32;
            na = v0 ? *reinterpret_cast<const u32x4*>(&aP[rb0 + ko])     : zz;
            nb = v0 ? *reinterpret_cast<const u32x4*>(&aP[rb0 + ko + 4]) : zz;
        }
        #pragma unroll
        for (int ct = 0; ct < 8; ++ct) {
            const int ra = (kc * 8 + ct) * 512 + lane * 8;
            bf16x8 bh = *reinterpret_cast<const bf16x8*>(&wlds[ra]);
            bf16x8 bl = *reinterpret_cast<const bf16x8*>(&wlds[16384 + ra]);
            acc[ct] = __builtin_amdgcn_mfma_f32_16x16x32_bf16(bh, ah, acc[ct], 0, 0, 0);
            acc[ct] = __builtin_amdgcn_mfma_f32_16x16x32_bf16(bh, al, acc[ct], 0, 0, 0);
            acc[ct] = __builtin_amdgcn_mfma_f32_16x16x32_bf16(bl, ah, acc[ct], 0, 0, 0);
        }
        if (kc < 3) unpack8(na, nb, ah, al);
    }

    // ---- h1 = relu(acc + b1), packed in regs ----
    unsigned h1p[32];
    #pragma unroll
    for (int ct = 0; ct < 8; ++ct) {
        const int c0 = ct * 16 + lq * 4;
        float4 bv = *reinterpret_cast<const float4*>(&b1[c0]);
        h1p[ct * 4 + 0] = packbf(fmaxf(acc[ct][0] + bv.x, 0.f));
        h1p[ct * 4 + 1] = packbf(fmaxf(acc[ct][1] + bv.y, 0.f));
        h1p[ct * 4 + 2] = packbf(fmaxf(acc[ct][2] + bv.z, 0.f));
        h1p[ct * 4 + 3] = packbf(fmaxf(acc[ct][3] + bv.w, 0.f));
    }

    // ---- stage W2 over W1 ----
    __syncthreads();   // all W1 LDS reads complete
    {
        const bf16x8* src = reinterpret_cast<const bf16x8*>(Wf2);
        bf16x8* dst = reinterpret_cast<bf16x8*>(wlds);
        #pragma unroll
        for (int it = 0; it < 8; ++it)
            dst[it * 512 + tid] = src[it * 512 + tid];
    }
    __syncthreads();

    // ---- GEMM2: B-frag from h1p via 4-lane shfl ----
    f32x4 acc2[8] = {};
    const int aown = (lq & 1) * 2;
    const bool hi_t = (lq & 2) != 0;
    #pragma unroll
    for (int kc = 0; kc < 4; ++kc) {
        unsigned pd[8];
        #pragma unroll
        for (int m = 0; m < 4; ++m) {
            unsigned vA = h1p[(2 * kc) * 4 + m];
            unsigned vB = h1p[(2 * kc + 1) * 4 + m];
            unsigned sA0 = __shfl(vA, lr + 16 * aown);
            unsigned sB0 = __shfl(vB, lr + 16 * aown);
            unsigned sA1 = __shfl(vA, lr + 16 * (aown + 1));
            unsigned sB1 = __shfl(vB, lr + 16 * (aown + 1));
            pd[m]     = hi_t ? sB0 : sA0;
            pd[4 + m] = hi_t ? sB1 : sA1;
        }
        u32x4 qa = {pd[0], pd[1], pd[2], pd[3]};
        u32x4 qb = {pd[4], pd[5], pd[6], pd[7]};
        bf16x8 hh, hl;
        unpack8(qa, qb, hh, hl);
        #pragma unroll
        for (int ct = 0; ct < 8; ++ct) {
            const int ra = (kc * 8 + ct) * 512 + lane * 8;
            bf16x8 bh = *reinterpret_cast<const bf16x8*>(&wlds[ra]);
            bf16x8 bl = *reinterpret_cast<const bf16x8*>(&wlds[16384 + ra]);
            acc2[ct] = __builtin_amdgcn_mfma_f32_16x16x32_bf16(bh, hh, acc2[ct], 0, 0, 0);
            acc2[ct] = __builtin_amdgcn_mfma_f32_16x16x32_bf16(bh, hl, acc2[ct], 0, 0, 0);
            acc2[ct] = __builtin_amdgcn_mfma_f32_16x16x32_bf16(bl, hh, acc2[ct], 0, 0, 0);
        }
    }

    // ---- epilogue: fp32 out ----
    if (v0) {
        #pragma unroll
        for (int ct = 0; ct < 8; ++ct) {
            const int c0 = ct * 16 + lq * 4;
            float4 bv = *reinterpret_cast<const float4*>(&b2[c0]);
            float4 o;
            o.x = fmaxf(acc2[ct][0] + bv.x, 0.f);
            o.y = fmaxf(acc2[ct][1] + bv.y, 0.f);
            o.z = fmaxf(acc2[ct][2] + bv.z, 0.f);
            o.w = fmaxf(acc2[ct][3] + bv.w, 0.f);
            *reinterpret_cast<float4*>(&outC[(size_t)n0 * FEAT + c0]) = o;
        }
    }
}

// ==================== pooling ====================
__global__ __launch_bounds__(512)
void pool_kernel(const float* __restrict__ y, const int* __restrict__ batch,
                 float* __restrict__ out, int n_nodes, int layer)
{
    const int g = blockIdx.x;
    int lo = 0, hi = n_nodes;
    while (lo < hi) { int mid = (lo + hi) >> 1; if (batch[mid] < g) lo = mid + 1; else hi = mid; }
    const int start = lo;
    hi = n_nodes;
    while (lo < hi) { int mid = (lo + hi) >> 1; if (batch[mid] < g + 1) lo = mid + 1; else hi = mid; }
    const int end = lo;

    const int tid = threadIdx.x;
    const int f = tid & 127;
    const int q = tid >> 7;
    float sum = 0.f;
    for (int n = start + q; n < end; n += 4)
        sum += y[(size_t)n * FEAT + f];

    __shared__ float red[512];
    red[tid] = sum;
    __syncthreads();
    if (tid < 128)
        out[g * (3 * FEAT) + layer * FEAT + tid]
            = red[tid] + red[tid + 128] + red[tid + 256] + red[tid + 384];
}

// ==================== fallback path kernels (ws too small) ====================
__global__ __launch_bounds__(256)
void scatter_kernel(const float* __restrict__ h, const int* __restrict__ ei,
                    float* __restrict__ agg, int n_edges)
{
    int e = blockIdx.x * 4 + (threadIdx.x >> 6);
    if (e >= n_edges) return;
    int lane = threadIdx.x & 63;
    int s = ei[e];
    int d = ei[n_edges + e];
    float2 v = reinterpret_cast<const float2*>(h + (size_t)s * FEAT)[lane];
    float* ap = agg + (size_t)d * FEAT + lane * 2;
    atomicAdd(ap, v.x);
    atomicAdd(ap + 1, v.y);
}

__global__ __launch_bounds__(256)
void combine_kernel(const float* __restrict__ h, float* __restrict__ agg_xeff, size_t n4)
{
    size_t i = (size_t)blockIdx.x * 256 + threadIdx.x;
    if (i >= n4) return;
    float4 a = reinterpret_cast<const float4*>(h)[i];
    float4 g = reinterpret_cast<float4*>(agg_xeff)[i];
    float4 o;
    o.x = (a.x + g.x) * 0.5f + a.x;
    o.y = (a.y + g.y) * 0.5f + a.y;
    o.z = (a.z + g.z) * 0.5f + a.z;
    o.w = (a.w + g.w) * 0.5f + a.w;
    reinterpret_cast<float4*>(agg_xeff)[i] = o;
}

__global__ __launch_bounds__(256, 2)
void gemm_relu_kernel(const float* __restrict__ A, const float* __restrict__ W,
                      const float* __restrict__ bias, float* __restrict__ out, int n_nodes)
{
    __shared__ float xt[64][128];
    __shared__ float wt[64][128];
    const int tid = threadIdx.x;
    const int row0 = blockIdx.x * 128;
    const int r  = tid >> 1;
    const int ks = (tid & 1) << 5;
    const int tn = (tid >> 4) << 3;
    const int to = (tid & 15) << 3;
    float acc[8][8] = {};

    for (int c = 0; c < 2; ++c) {
        const int k0 = c * 64;
        {
            const float4* wrow = reinterpret_cast<const float4*>(W + r * FEAT + k0 + ks);
            #pragma unroll
            for (int i = 0; i < 8; ++i) {
                float4 w4 = wrow[i];
                int kk = ks + i * 4;
                wt[kk + 0][r] = w4.x; wt[kk + 1][r] = w4.y;
                wt[kk + 2][r] = w4.z; wt[kk + 3][r] = w4.w;
            }
        }
        {
            const int n = row0 + r;
            if (n < n_nodes) {
                const float4* ar = reinterpret_cast<const float4*>(A + (size_t)n * FEAT + k0 + ks);
                #pragma unroll
                for (int i = 0; i < 8; ++i) {
                    float4 a4 = ar[i];
                    int kk = ks + i * 4;
                    xt[kk + 0][r] = a4.x; xt[kk + 1][r] = a4.y;
                    xt[kk + 2][r] = a4.z; xt[kk + 3][r] = a4.w;
                }
            } else {
                #pragma unroll
                for (int i = 0; i < 8; ++i) {
                    int kk = ks + i * 4;
                    xt[kk + 0][r] = 0.f; xt[kk + 1][r] = 0.f;
                    xt[kk + 2][r] = 0.f; xt[kk + 3][r] = 0.f;
                }
            }
        }
        __syncthreads();
        #pragma unroll 4
        for (int k = 0; k < 64; ++k) {
            float4 x0 = *reinterpret_cast<const float4*>(&xt[k][tn]);
            float4 x1 = *reinterpret_cast<const float4*>(&xt[k][tn + 4]);
            float4 w0 = *reinterpret_cast<const float4*>(&wt[k][to]);
            float4 w1 = *reinterpret_cast<const float4*>(&wt[k][to + 4]);
            float xv[8] = {x0.x, x0.y, x0.z, x0.w, x1.x, x1.y, x1.z, x1.w};
            float wv[8] = {w0.x, w0.y, w0.z, w0.w, w1.x, w1.y, w1.z, w1.w};
            #pragma unroll
            for (int i = 0; i < 8; ++i)
                #pragma unroll
                for (int j = 0; j < 8; ++j)
                    acc[i][j] = fmaf(xv[i], wv[j], acc[i][j]);
        }
        __syncthreads();
    }

    float bv[8];
    #pragma unroll
    for (int j = 0; j < 8; ++j) bv[j] = bias[to + j];
    #pragma unroll
    for (int i = 0; i < 8; ++i) {
        int n = row0 + tn + i;
        if (n >= n_nodes) break;
        float4 o0, o1;
        o0.x = fmaxf(acc[i][0] + bv[0], 0.f);
        o0.y = fmaxf(acc[i][1] + bv[1], 0.f);
        o0.z = fmaxf(acc[i][2] + bv[2], 0.f);
        o0.w = fmaxf(acc[i][3] + bv[3], 0.f);
        o1.x = fmaxf(acc[i][4] + bv[4], 0.f);
        o1.y = fmaxf(acc[i][5] + bv[5], 0.f);
        o1.z = fmaxf(acc[i][6] + bv[6], 0.f);
        o1.w = fmaxf(acc[i][7] + bv[7], 0.f);
        float* op = out + (size_t)n * FEAT + to;
        *reinterpret_cast<float4*>(op) = o0;
        *reinterpret_cast<float4*>(op + 4) = o1;
    }
}

extern "C" void kernel_launch(void* const* d_in, const int* in_sizes, int n_in,
                              void* d_out, int out_size, void* d_ws, size_t ws_size,
                              hipStream_t stream)
{
    const float* x     = (const float*)d_in[0];
    const int*   ei    = (const int*)d_in[1];
    const int*   batch = (const int*)d_in[2];
    const float* W1[3] = {(const float*)d_in[4], (const float*)d_in[8],  (const float*)d_in[12]};
    const float* b1[3] = {(const float*)d_in[5], (const float*)d_in[9],  (const float*)d_in[13]};
    const float* W2[3] = {(const float*)d_in[6], (const float*)d_in[10], (const float*)d_in[14]};
    const float* b2[3] = {(const float*)d_in[7], (const float*)d_in[11], (const float*)d_in[15]};

    const size_t nf = (size_t)NN * FEAT;
    float* outp = (float*)d_out;
    const int fused_grid = (NN + 127) / 128;         // 782
    const int M = NB * NCHUNK;                       // 78400
    const int scanM_blocks = (M + 1023) / 1024;      // 77
    const int WN = FEAT * FEAT;                      // 16384

    const size_t need_full = 2 * nf * 4 + (size_t)(NN + 1 + NE) * 4 + (size_t)12 * WN * 2;

    if (ws_size >= need_full) {
        unsigned* xeffP = (unsigned*)d_ws;       // nf dwords (hi|lo packed)
        float* bufC     = (float*)(xeffP + nf);  // nf floats (layer output)
        int* off        = (int*)(bufC + nf);     // NN+1
        int* csr        = off + (NN + 1);        // NE
        short* wbase    = (short*)(csr + NE);    // 12 * WN shorts
        short* wf[6];
        for (int i = 0; i < 6; ++i) wf[i] = wbase + (size_t)i * 2 * WN;
        // build transients aliased (written only during build, before layer compute)
        int* cnt_T  = (int*)xeffP;               // M
        int* offs_T = cnt_T + M;                 // M
        int* bsum   = offs_T + M;                // 77
        int2* ebuf  = (int2*)bufC;               // NE pairs (12.8 MB < 51.2 MB)

        const float* Ws[6] = {W1[0], W2[0], W1[1], W2[1], W1[2], W2[2]};
        for (int i = 0; i < 6; ++i)
            wsplit_frag_kernel<<<WN / 256, 256, 0, stream>>>(Ws[i], wf[i]);

        p1a_count<<<NCHUNK, 256, 0, stream>>>(ei, cnt_T);
        scan1_kernel<<<scanM_blocks, 1024, 0, stream>>>(cnt_T, offs_T, bsum, M);
        scan2_kernel<<<1, 128, 0, stream>>>(bsum, scanM_blocks);
        scan3g_kernel<<<scanM_blocks, 1024, 0, stream>>>(offs_T, bsum, M);
        p1b_scatter<<<NCHUNK, 256, 0, stream>>>(ei, offs_T, ebuf);
        p2_csr<<<NB, 512, 0, stream>>>(ebuf, offs_T, off, csr);

        const float* h = x;
        for (int l = 0; l < 3; ++l) {
            aggregate_pack_kernel<<<(NN + 3) / 4, 256, 0, stream>>>(h, off, csr, xeffP, NN);
            layer_fused_kernel<<<fused_grid, 512, 0, stream>>>(xeffP, wf[2 * l], wf[2 * l + 1],
                                                               b1[l], b2[l], bufC, NN);
            pool_kernel<<<NGRAPH, 512, 0, stream>>>(bufC, batch, outp, NN, l);
            h = bufC;
        }
    } else if (ws_size >= 3 * nf * 4) {
        float* bufA = (float*)d_ws;
        float* bufB = bufA + nf;
        float* bufC = bufB + nf;
        const int gg = (NN + 127) / 128;
        const float* h = x;
        for (int l = 0; l < 3; ++l) {
            hipMemsetAsync(bufA, 0, nf * 4, stream);
            scatter_kernel<<<(NE + 3) / 4, 256, 0, stream>>>(h, ei, bufA, NE);
            combine_kernel<<<(int)((nf / 4 + 255) / 256), 256, 0, stream>>>(h, bufA, nf / 4);
            gemm_relu_kernel<<<gg, 256, 0, stream>>>(bufA, W1[l], b1[l], bufB, NN);
            gemm_relu_kernel<<<gg, 256, 0, stream>>>(bufB, W2[l], b2[l], bufC, NN);
            pool_kernel<<<NGRAPH, 512, 0, stream>>>(bufC, batch, outp, NN, l);
            h = bufC;
        }
    }
}